// Round 1
// baseline (1313.904 us; speedup 1.0000x reference)
//
#include <hip/hip_runtime.h>
#include <stdint.h>

typedef __attribute__((ext_vector_type(8))) short short8;
typedef __attribute__((ext_vector_type(4))) float f32x4;

#define DEVINL __device__ __forceinline__

DEVINL unsigned short f2bf(float x) {
  uint32_t b = __float_as_uint(x);
  b += 0x7fffu + ((b >> 16) & 1u);
  return (unsigned short)(b >> 16);
}
DEVINL float bf2f(unsigned short u) {
  return __uint_as_float(((uint32_t)u) << 16);
}

DEVINL void gll16(const void* g, void* l) {
  __builtin_amdgcn_global_load_lds(
      (const __attribute__((address_space(1))) uint32_t*)g,
      (__attribute__((address_space(3))) uint32_t*)l, 16, 0, 0);
}

__global__ void cvt_w_bf16(const float* __restrict__ in,
                           unsigned short* __restrict__ out, int n) {
  int i = blockIdx.x * blockDim.x + threadIdx.x;
  int stride = gridDim.x * blockDim.x;
  for (; i < n; i += stride) out[i] = f2bf(in[i]);
}

// C = epilogue(A[M,K] * Bw[N,K]^T)
// A_F32: A is f32 (convert to bf16 during staging), else bf16.
// NORM: multiply each output row by 1/(||A_row||+1e-8) before bias (norm computed
//       from the staged A values over the full K loop).
// RELU: relu after bias. OUT_BF16: store bf16, else f32.
template <int BM, int BN, int WM, int WN, bool A_F32, bool NORM, bool RELU, bool OUT_BF16>
__global__ __launch_bounds__(256) void gemm_ff(
    const void* __restrict__ Aptr, const unsigned short* __restrict__ Bw,
    const float* __restrict__ bias, void* __restrict__ Cptr,
    int M, int N, int K) {
  constexpr int BK = 32;
  constexpr int PTA = BM * 4 / 256;  // 16B segments of A tile per thread
  constexpr int PTB = BN * 4 / 256;
  __shared__ short As[BM * BK];
  __shared__ short Bs[BN * BK];
  __shared__ float red[NORM ? BM * 4 : 4];
  __shared__ float scale_lds[NORM ? BM : 4];

  const int t = threadIdx.x;
  const int lane = t & 63;
  const int wid = t >> 6;
  const int wr = wid / WN;
  const int wc = wid % WN;
  const int bm = blockIdx.x;
  const int bn = blockIdx.y;

  f32x4 acc[4][4] = {};
  float ssq[PTA];
#pragma unroll
  for (int r = 0; r < PTA; ++r) ssq[r] = 0.f;

  const int kIters = K / BK;
  for (int kk = 0; kk < kIters; ++kk) {
    const int k0 = kk * BK;
    // ---- stage B tile [BN][BK] via global_load_lds (16B per lane) ----
#pragma unroll
    for (int r = 0; r < PTB; ++r) {
      const int s = r * 256 + t;
      const int n = s >> 2;
      const int ks = (s & 3) * 8;
      gll16(Bw + (size_t)(bn * BN + n) * K + k0 + ks, &Bs[s * 8]);
    }
    // ---- stage A tile [BM][BK] via registers (convert + ssq) ----
    if constexpr (A_F32) {
      const float* Af = (const float*)Aptr;
#pragma unroll
      for (int r = 0; r < PTA; ++r) {
        const int s = r * 256 + t;
        const int row = s >> 2;
        const int ks = (s & 3) * 8;
        const float* g = Af + (size_t)(bm * BM + row) * K + k0 + ks;
        f32x4 v0 = *(const f32x4*)g;
        f32x4 v1 = *(const f32x4*)(g + 4);
        short8 u;
#pragma unroll
        for (int j = 0; j < 4; ++j) {
          u[j] = (short)f2bf(v0[j]);
          u[4 + j] = (short)f2bf(v1[j]);
        }
        if constexpr (NORM) {
#pragma unroll
          for (int j = 0; j < 4; ++j) ssq[r] += v0[j] * v0[j] + v1[j] * v1[j];
        }
        *(short8*)&As[s * 8] = u;
      }
    } else {
      const unsigned short* Ab = (const unsigned short*)Aptr;
#pragma unroll
      for (int r = 0; r < PTA; ++r) {
        const int s = r * 256 + t;
        const int row = s >> 2;
        const int ks = (s & 3) * 8;
        const short8 u = *(const short8*)(Ab + (size_t)(bm * BM + row) * K + k0 + ks);
        if constexpr (NORM) {
#pragma unroll
          for (int j = 0; j < 8; ++j) {
            float f = bf2f((unsigned short)u[j]);
            ssq[r] += f * f;
          }
        }
        *(short8*)&As[s * 8] = u;
      }
    }
    __syncthreads();
    // ---- compute: each wave does 64x64 via 4x4 frags of 16x16x32 ----
    short8 af[4], bfg[4];
#pragma unroll
    for (int m = 0; m < 4; ++m)
      af[m] = *(const short8*)&As[(wr * 64 + m * 16 + (lane & 15)) * BK + ((lane >> 4) * 8)];
#pragma unroll
    for (int n = 0; n < 4; ++n)
      bfg[n] = *(const short8*)&Bs[(wc * 64 + n * 16 + (lane & 15)) * BK + ((lane >> 4) * 8)];
#pragma unroll
    for (int m = 0; m < 4; ++m)
#pragma unroll
      for (int n = 0; n < 4; ++n)
        acc[m][n] = __builtin_amdgcn_mfma_f32_16x16x32_bf16(af[m], bfg[n], acc[m][n], 0, 0, 0);
    __syncthreads();
  }

  if constexpr (NORM) {
#pragma unroll
    for (int r = 0; r < PTA; ++r) red[r * 256 + t] = ssq[r];
    __syncthreads();
    if (t < BM) {
      float tot = red[t * 4] + red[t * 4 + 1] + red[t * 4 + 2] + red[t * 4 + 3];
      scale_lds[t] = 1.0f / (sqrtf(tot) + 1e-8f);
    }
    __syncthreads();
  }

  // ---- epilogue: C row = (lane>>4)*4+j, col = lane&15 within each 16x16 frag ----
#pragma unroll
  for (int m = 0; m < 4; ++m) {
#pragma unroll
    for (int j = 0; j < 4; ++j) {
      const int rl = wr * 64 + m * 16 + ((lane >> 4) << 2) + j;
      const size_t row = (size_t)bm * BM + rl;
      float sc = 1.0f;
      if constexpr (NORM) sc = scale_lds[rl];
#pragma unroll
      for (int n = 0; n < 4; ++n) {
        const int col = bn * BN + wc * 64 + n * 16 + (lane & 15);
        float v = acc[m][n][j];
        if constexpr (NORM) v *= sc;
        v += bias[col];
        if constexpr (RELU) v = fmaxf(v, 0.f);
        if constexpr (OUT_BF16)
          ((unsigned short*)Cptr)[row * (size_t)N + col] = f2bf(v);
        else
          ((float*)Cptr)[row * (size_t)N + col] = v;
      }
    }
  }
}

extern "C" void kernel_launch(void* const* d_in, const int* in_sizes, int n_in,
                              void* d_out, int out_size, void* d_ws, size_t ws_size,
                              hipStream_t stream) {
  const float* states = (const float*)d_in[0];
  const float* W1 = (const float*)d_in[1];
  const float* b1 = (const float*)d_in[2];
  const float* W2 = (const float*)d_in[3];
  const float* b2 = (const float*)d_in[4];
  const float* Wq = (const float*)d_in[5];
  const float* bq = (const float*)d_in[6];
  float* out = (float*)d_out;

  const int D = 1024, H1 = 2048, H2 = 1024, A = 64;
  const int B = in_sizes[0] / D;

  unsigned short* W1b = (unsigned short*)d_ws;           // [H1][D]
  unsigned short* W2b = W1b + (size_t)H1 * D;            // [H2][H1]
  unsigned short* Wqb = W2b + (size_t)H2 * H1;           // [A][H2]
  unsigned short* h1 = Wqb + (size_t)A * H2;

  const size_t wbytes = ((size_t)H1 * D + (size_t)H2 * H1 + (size_t)A * H2) * 2;
  size_t avail = ws_size > wbytes ? ws_size - wbytes : 0;
  long long bc = (long long)(avail / ((size_t)(H1 + H2) * 2));
  bc = (bc / 256) * 256;
  if (bc <= 0) bc = 256;
  if (bc > B) bc = B;
  unsigned short* h2 = h1 + (size_t)bc * H1;

  // convert weights to bf16 once per call (deterministic)
  cvt_w_bf16<<<dim3(1024), dim3(256), 0, stream>>>(W1, W1b, H1 * D);
  cvt_w_bf16<<<dim3(1024), dim3(256), 0, stream>>>(W2, W2b, H2 * H1);
  cvt_w_bf16<<<dim3(64), dim3(256), 0, stream>>>(Wq, Wqb, A * H2);

  for (int off = 0; off < B; off += (int)bc) {
    const int cur = (B - off) < (int)bc ? (B - off) : (int)bc;
    // G1: h1 = relu((states/|states|)·W1^T + b1)
    gemm_ff<128, 128, 2, 2, true, true, true, true>
        <<<dim3(cur / 128, H1 / 128), dim3(256), 0, stream>>>(
            states + (size_t)off * D, W1b, b1, h1, cur, H1, D);
    // G2: h2 = relu((h1/|h1|)·W2^T + b2)
    gemm_ff<128, 128, 2, 2, false, true, true, true>
        <<<dim3(cur / 128, H2 / 128), dim3(256), 0, stream>>>(
            h1, W2b, b2, h2, cur, H2, H1);
    // G3: q = h2·Wq^T + bq
    gemm_ff<256, 64, 4, 1, false, false, false, false>
        <<<dim3(cur / 256, 1), dim3(256), 0, stream>>>(
            h2, Wqb, bq, out + (size_t)off * A, cur, A, H2);
  }
}

// Round 2
// 1012.960 us; speedup vs baseline: 1.2971x; 1.2971x over previous
//
#include <hip/hip_runtime.h>
#include <stdint.h>

typedef __attribute__((ext_vector_type(8))) short short8;
typedef __attribute__((ext_vector_type(4))) short short4v;
typedef __attribute__((ext_vector_type(4))) float f32x4;

#define DEVINL __device__ __forceinline__

DEVINL unsigned short f2bf(float x) {
  uint32_t b = __float_as_uint(x);
  b += 0x7fffu + ((b >> 16) & 1u);
  return (unsigned short)(b >> 16);
}
DEVINL float bf2f(unsigned short u) {
  return __uint_as_float(((uint32_t)u) << 16);
}

DEVINL void gll16(const void* g, void* l) {
  __builtin_amdgcn_global_load_lds(
      (const __attribute__((address_space(1))) uint32_t*)g,
      (__attribute__((address_space(3))) uint32_t*)l, 16, 0, 0);
}

__global__ void cvt_w_bf16(const float* __restrict__ in,
                           unsigned short* __restrict__ out, int n) {
  int i = blockIdx.x * blockDim.x + threadIdx.x;
  int stride = gridDim.x * blockDim.x;
  for (; i < n; i += stride) out[i] = f2bf(in[i]);
}

// wave-per-row: out_row = bf16(in_row / (||in_row|| + eps))
template <int D>
__global__ __launch_bounds__(256) void norm_rows_f32(
    const float* __restrict__ in, unsigned short* __restrict__ out, int nrows) {
  const int lane = threadIdx.x & 63;
  const int row = blockIdx.x * 4 + (threadIdx.x >> 6);
  if (row >= nrows) return;
  const float* r = in + (size_t)row * D;
  constexpr int NSEG = D / 256;  // f32x4 segments per lane
  f32x4 v[NSEG];
  float ssq = 0.f;
#pragma unroll
  for (int i = 0; i < NSEG; ++i) {
    v[i] = *(const f32x4*)(r + (i * 64 + lane) * 4);
#pragma unroll
    for (int j = 0; j < 4; ++j) ssq += v[i][j] * v[i][j];
  }
#pragma unroll
  for (int m = 32; m >= 1; m >>= 1) ssq += __shfl_xor(ssq, m, 64);
  const float sc = 1.0f / (sqrtf(ssq) + 1e-8f);
  unsigned short* o = out + (size_t)row * D;
#pragma unroll
  for (int i = 0; i < NSEG; ++i) {
    short4v u;
#pragma unroll
    for (int j = 0; j < 4; ++j) u[j] = (short)f2bf(v[i][j] * sc);
    *(short4v*)(o + (i * 64 + lane) * 4) = u;
  }
}

// wave-per-row: scale[row] = 1/(||bf16 row|| + eps)
template <int H>
__global__ __launch_bounds__(256) void rownorm_bf16(
    const unsigned short* __restrict__ in, float* __restrict__ scale, int nrows) {
  const int lane = threadIdx.x & 63;
  const int row = blockIdx.x * 4 + (threadIdx.x >> 6);
  if (row >= nrows) return;
  const unsigned short* r = in + (size_t)row * H;
  constexpr int NSEG = H / 512;  // short8 segments per lane
  float ssq = 0.f;
#pragma unroll
  for (int i = 0; i < NSEG; ++i) {
    short8 u = *(const short8*)(r + (i * 64 + lane) * 8);
#pragma unroll
    for (int j = 0; j < 8; ++j) {
      float f = bf2f((unsigned short)u[j]);
      ssq += f * f;
    }
  }
#pragma unroll
  for (int m = 32; m >= 1; m >>= 1) ssq += __shfl_xor(ssq, m, 64);
  if (lane == 0) scale[row] = 1.0f / (sqrtf(ssq) + 1e-8f);
}

// C = epilogue(A[M,K](bf16) * Bw[N,K]^T(bf16)); SCALE: mult row by scaleArr[row]
// before bias. 4 waves; each wave computes 64x64 (WN waves across N).
// 1D grid, bn-fastest ordering + bijective XCD swizzle for L2 locality.
template <int BM, int BN, int WN, bool SCALE, bool RELU, bool OUT_BF16>
__global__ __launch_bounds__(256) void gemm_ff(
    const unsigned short* __restrict__ A, const unsigned short* __restrict__ Bw,
    const float* __restrict__ bias, const float* __restrict__ scaleArr,
    void* __restrict__ Cptr, int M, int N, int K) {
  constexpr int BK = 32;
  constexpr int PTA = BM / 64;  // 16B segments of A tile per thread
  constexpr int PTB = BN / 64;
  __shared__ short As[BM * BK];
  __shared__ short Bs[BN * BK];

  const int t = threadIdx.x;
  const int lane = t & 63;
  const int wid = t >> 6;
  const int wr = wid / WN;
  const int wc = wid % WN;

  const int nwg = gridDim.x;
  const int bid = blockIdx.x;
  int wg = bid;
  if ((nwg & 7) == 0) wg = (bid & 7) * (nwg >> 3) + (bid >> 3);
  const int numBN = N / BN;
  const int bm = wg / numBN;
  const int bn = wg % numBN;

  f32x4 acc[4][4] = {};

  const unsigned short* Abase = A + (size_t)bm * BM * K;
  const unsigned short* Bbase = Bw + (size_t)bn * BN * K;
  const int kIters = K / BK;
  for (int kk = 0; kk < kIters; ++kk) {
    const int k0 = kk * BK;
#pragma unroll
    for (int r = 0; r < PTB; ++r) {
      const int s = r * 256 + t;
      gll16(Bbase + (size_t)(s >> 2) * K + k0 + (s & 3) * 8, &Bs[s * 8]);
    }
#pragma unroll
    for (int r = 0; r < PTA; ++r) {
      const int s = r * 256 + t;
      gll16(Abase + (size_t)(s >> 2) * K + k0 + (s & 3) * 8, &As[s * 8]);
    }
    __syncthreads();
    short8 af[4], bfg[4];
#pragma unroll
    for (int m = 0; m < 4; ++m)
      af[m] = *(const short8*)&As[(wr * 64 + m * 16 + (lane & 15)) * BK + ((lane >> 4) * 8)];
#pragma unroll
    for (int n = 0; n < 4; ++n)
      bfg[n] = *(const short8*)&Bs[(wc * 64 + n * 16 + (lane & 15)) * BK + ((lane >> 4) * 8)];
#pragma unroll
    for (int m = 0; m < 4; ++m)
#pragma unroll
      for (int n = 0; n < 4; ++n)
        acc[m][n] = __builtin_amdgcn_mfma_f32_16x16x32_bf16(af[m], bfg[n], acc[m][n], 0, 0, 0);
    __syncthreads();
  }

  // C frag: row=(lane>>4)*4+j, col=lane&15 (m89-verified layout)
#pragma unroll
  for (int m = 0; m < 4; ++m) {
#pragma unroll
    for (int j = 0; j < 4; ++j) {
      const int rl = wr * 64 + m * 16 + ((lane >> 4) << 2) + j;
      const size_t row = (size_t)bm * BM + rl;
      float sc = 1.0f;
      if constexpr (SCALE) sc = scaleArr[row];
#pragma unroll
      for (int n = 0; n < 4; ++n) {
        const int col = bn * BN + wc * 64 + n * 16 + (lane & 15);
        float v = acc[m][n][j];
        if constexpr (SCALE) v *= sc;
        v += bias[col];
        if constexpr (RELU) v = fmaxf(v, 0.f);
        if constexpr (OUT_BF16)
          ((unsigned short*)Cptr)[row * (size_t)N + col] = f2bf(v);
        else
          ((float*)Cptr)[row * (size_t)N + col] = v;
      }
    }
  }
}

extern "C" void kernel_launch(void* const* d_in, const int* in_sizes, int n_in,
                              void* d_out, int out_size, void* d_ws, size_t ws_size,
                              hipStream_t stream) {
  const float* states = (const float*)d_in[0];
  const float* W1 = (const float*)d_in[1];
  const float* b1 = (const float*)d_in[2];
  const float* W2 = (const float*)d_in[3];
  const float* b2 = (const float*)d_in[4];
  const float* Wq = (const float*)d_in[5];
  const float* bq = (const float*)d_in[6];
  float* out = (float*)d_out;

  const int D = 1024, H1 = 2048, H2 = 1024, AO = 64;
  const int B = in_sizes[0] / D;

  unsigned short* W1b = (unsigned short*)d_ws;  // [H1][D]
  unsigned short* W2b = W1b + (size_t)H1 * D;   // [H2][H1]
  unsigned short* Wqb = W2b + (size_t)H2 * H1;  // [AO][H2]
  char* dynbase = (char*)(Wqb + (size_t)AO * H2);

  const size_t wbytes = ((size_t)H1 * D + (size_t)H2 * H1 + (size_t)AO * H2) * 2;
  size_t avail = ws_size > wbytes ? ws_size - wbytes : 0;
  // per-row: scale(4) + states_n(D*2) + h1(H1*2) + h2(H2*2)
  const size_t per_row = 4 + (size_t)(D + H1 + H2) * 2;
  long long bc = (long long)(avail / per_row);
  bc = (bc / 256) * 256;
  if (bc <= 0) bc = 256;
  if (bc > B) bc = B;

  float* scale1 = (float*)dynbase;
  unsigned short* sn = (unsigned short*)(scale1 + bc);
  unsigned short* h1 = sn + (size_t)bc * D;
  unsigned short* h2 = h1 + (size_t)bc * H1;

  cvt_w_bf16<<<dim3(1024), dim3(256), 0, stream>>>(W1, W1b, H1 * D);
  cvt_w_bf16<<<dim3(1024), dim3(256), 0, stream>>>(W2, W2b, H2 * H1);
  cvt_w_bf16<<<dim3(64), dim3(256), 0, stream>>>(Wq, Wqb, AO * H2);

  for (int off = 0; off < B; off += (int)bc) {
    const int cur = (B - off) < (int)bc ? (B - off) : (int)bc;
    // normalize states chunk -> bf16
    norm_rows_f32<1024><<<dim3(cur / 4), dim3(256), 0, stream>>>(
        states + (size_t)off * D, sn, cur);
    // G1: h1 = relu(sn·W1^T + b1)   (sn already normalized)
    gemm_ff<128, 128, 2, false, true, true>
        <<<dim3((cur / 128) * (H1 / 128)), dim3(256), 0, stream>>>(
            sn, W1b, b1, nullptr, h1, cur, H1, D);
    // scale1[row] = 1/(||h1 row||+eps)
    rownorm_bf16<2048><<<dim3(cur / 4), dim3(256), 0, stream>>>(h1, scale1, cur);
    // G2: h2 = relu(scale1·(h1·W2^T) + b2)
    gemm_ff<128, 128, 2, true, true, true>
        <<<dim3((cur / 128) * (H2 / 128)), dim3(256), 0, stream>>>(
            h1, W2b, b2, scale1, h2, cur, H2, H1);
    // G3: q = h2·Wq^T + bq
    gemm_ff<256, 64, 1, false, false, false>
        <<<dim3(cur / 256), dim3(256), 0, stream>>>(
            h2, Wqb, bq, nullptr, out + (size_t)off * AO, cur, AO, H2);
  }
}